// Round 6
// baseline (463.816 us; speedup 1.0000x reference)
//
#include <hip/hip_runtime.h>
#include <hip/hip_bf16.h>
#include <math.h>

#define B_ROWS 8192
#define DDIM   1024
#define NEXP   8

typedef __attribute__((ext_vector_type(8))) __bf16 bf16x8;
typedef __attribute__((ext_vector_type(4))) float  f32x4;

__device__ __forceinline__ unsigned short f2bf(float f) {
    // round-to-nearest-even f32 -> bf16
    unsigned u = __builtin_bit_cast(unsigned, f);
    u = (u + 0x7fffu + ((u >> 16) & 1u)) >> 16;
    return (unsigned short)u;
}

// async global->LDS, 16B per lane; LDS dest = wave-uniform base + lane*16
#define GLOAD_LDS16(gptr, lptr)                                                \
    __builtin_amdgcn_global_load_lds(                                          \
        (const __attribute__((address_space(1))) unsigned int*)(gptr),         \
        (__attribute__((address_space(3))) unsigned int*)(lptr), 16, 0, 0)

// ---------------------------------------------------------------------------
// Pre-pass A: x (f32) -> xbf (bf16), 8M elements.
// ---------------------------------------------------------------------------
__global__ __launch_bounds__(256) void xconv_kernel(
    const float* __restrict__ x, __hip_bfloat16* __restrict__ xbf)
{
    int i = blockIdx.x * 256 + threadIdx.x;
    const int stride = gridDim.x * 256;
    const int n8 = B_ROWS * DDIM / 8;
    for (; i < n8; i += stride) {
        const float4 f0 = *(const float4*)(x + (size_t)i * 8);
        const float4 f1 = *(const float4*)(x + (size_t)i * 8 + 4);
        union { bf16x8 v; unsigned short u[8]; } pk;
        pk.u[0] = f2bf(f0.x); pk.u[1] = f2bf(f0.y); pk.u[2] = f2bf(f0.z); pk.u[3] = f2bf(f0.w);
        pk.u[4] = f2bf(f1.x); pk.u[5] = f2bf(f1.y); pk.u[6] = f2bf(f1.z); pk.u[7] = f2bf(f1.w);
        *(bf16x8*)((__hip_bfloat16*)xbf + (size_t)i * 8) = pk.v;
    }
}

// ---------------------------------------------------------------------------
// Pre-pass B: W [e][k][n] f32 -> Wt [e][n][k] bf16 via 64x64 LDS tile.
// ---------------------------------------------------------------------------
__global__ __launch_bounds__(256) void wtrans_kernel(
    const float* __restrict__ W, __hip_bfloat16* __restrict__ Wt)
{
    const int e  = blockIdx.z;
    const int k0 = blockIdx.y * 64;
    const int n0 = blockIdx.x * 64;
    __shared__ float st[64][65];          // +1 pad

    const int t = threadIdx.x;
    {
        const int kk = t >> 4;
        const int nn = (t & 15) * 4;
#pragma unroll
        for (int p = 0; p < 4; ++p) {
            const int k = p * 16 + kk;
            const float4 v = *(const float4*)(W + (size_t)e * DDIM * DDIM
                                                + (size_t)(k0 + k) * DDIM + n0 + nn);
            st[k][nn + 0] = v.x; st[k][nn + 1] = v.y;
            st[k][nn + 2] = v.z; st[k][nn + 3] = v.w;
        }
    }
    __syncthreads();
    {
        const int wave = t >> 6, lane = t & 63;
        const int nr = lane >> 3, kc = lane & 7;
#pragma unroll
        for (int p = 0; p < 2; ++p) {
            const int n = p * 32 + wave * 8 + nr;
            union { bf16x8 v; unsigned short u[8]; } pk;
#pragma unroll
            for (int j = 0; j < 8; ++j) pk.u[j] = f2bf(st[kc * 8 + j][n]);
            *(bf16x8*)((__hip_bfloat16*)Wt + (size_t)e * DDIM * DDIM
                        + (size_t)(n0 + n) * DDIM + k0 + kc * 8) = pk.v;
        }
    }
}

// ---------------------------------------------------------------------------
// Pre-pass C: wt[c][k] f32, c: 0-7 = w_gate col c, 8-15 = w_noise col c-8.
// ---------------------------------------------------------------------------
__global__ __launch_bounds__(256) void wprep_kernel(
    const float* __restrict__ wg, const float* __restrict__ wn, float* __restrict__ wt)
{
    const int t = blockIdx.x * 256 + threadIdx.x;   // t = c*1024 + k
    if (t < 16 * DDIM) {
        const int c = t >> 10, k = t & 1023;
        wt[t] = (c < 8) ? wg[k * NEXP + c] : wn[k * NEXP + (c - 8)];
    }
}

// ---------------------------------------------------------------------------
// Kernel 1: gating v5 — ONE ROW PER WAVE (8192 waves -> 8 blocks/CU, TLP
// covers latency). Lane = (ks=lane>>4, c=lane&15): lane accumulates the
// 256-element K-slice ks of logit column c, 8 independent f64 accumulators.
// K-slices summed via shfl_xor 16/32 (closed groups, same c); then the
// verified top-2 butterfly on offsets 1/2/4.  f32 products + f64 accum ->
// selection matches the f64 numpy reference. rowlist entry = row|(rank<<31).
// ---------------------------------------------------------------------------
__global__ __launch_bounds__(256) void gating_kernel(
    const float* __restrict__ x, const float* __restrict__ noise,
    const float* __restrict__ wt,
    int* __restrict__ counts, int* __restrict__ rowlist, float* __restrict__ gatelist)
{
    const int t = threadIdx.x;
    const int wave = t >> 6, lane = t & 63;
    const int ks = lane >> 4, c = lane & 15;
    const int row = blockIdx.x * 4 + wave;

    const float* xr = x  + (size_t)row * DDIM + ks * 256;
    const float* wr = wt + (size_t)c   * DDIM + ks * 256;

    double a0 = 0, a1 = 0, a2 = 0, a3 = 0, a4 = 0, a5 = 0, a6 = 0, a7 = 0;
#pragma unroll 4
    for (int k8 = 0; k8 < 32; ++k8) {
        const float4 xv0 = *(const float4*)(xr + k8 * 8);
        const float4 xv1 = *(const float4*)(xr + k8 * 8 + 4);
        const float4 wv0 = *(const float4*)(wr + k8 * 8);
        const float4 wv1 = *(const float4*)(wr + k8 * 8 + 4);
        a0 += (double)(xv0.x * wv0.x);
        a1 += (double)(xv0.y * wv0.y);
        a2 += (double)(xv0.z * wv0.z);
        a3 += (double)(xv0.w * wv0.w);
        a4 += (double)(xv1.x * wv1.x);
        a5 += (double)(xv1.y * wv1.y);
        a6 += (double)(xv1.z * wv1.z);
        a7 += (double)(xv1.w * wv1.w);
    }
    double acc = ((a0 + a1) + (a2 + a3)) + ((a4 + a5) + (a6 + a7));

    // sum the 4 K-slices: offsets 16,32 close the group {same c, all ks}
    acc += __shfl_xor(acc, 16);
    acc += __shfl_xor(acc, 32);

    const double vnoise = __shfl_xor(acc, 8);     // partner column c^8

    double lgv = -1.0e300;
    if (c < 8) {
        const double z  = vnoise;
        const double sp = (z > 30.0) ? z : log1p(exp(z));
        lgv = acc + (double)noise[(size_t)row * NEXP + c] * (sp + 0.01);
    }

    // top-1 butterfly over the 8 logit lanes (offsets 1,2,4)
    double bv = lgv; int bi = c;
#pragma unroll
    for (int off = 1; off <= 4; off <<= 1) {
        const double ov = __shfl_xor(bv, off);
        const int    oi = __shfl_xor(bi, off);
        if (ov > bv || (ov == bv && oi < bi)) { bv = ov; bi = oi; }
    }
    // top-2: mask winner, reduce again
    double b2v = (c == bi) ? -1.0e300 : lgv; int b2i = c;
#pragma unroll
    for (int off = 1; off <= 4; off <<= 1) {
        const double ov = __shfl_xor(b2v, off);
        const int    oi = __shfl_xor(b2i, off);
        if (ov > b2v || (ov == b2v && oi < b2i)) { b2v = ov; b2i = oi; }
    }

    if (lane == 0) {
        const double g0 = 1.0 / (1.0 + exp(b2v - bv));
        const double g1 = 1.0 - g0;
        int p0 = atomicAdd(&counts[bi], 1);
        rowlist [bi * B_ROWS + p0] = row;                                 // rank 0
        gatelist[bi * B_ROWS + p0] = (float)g0;
        int p1 = atomicAdd(&counts[b2i], 1);
        rowlist [b2i * B_ROWS + p1] = (int)((unsigned)row | 0x80000000u); // rank 1
        gatelist[b2i * B_ROWS + p1] = (float)g1;
    }
}

// ---------------------------------------------------------------------------
// Kernel 2: grouped expert GEMM, 128x128 tile, BK=64, double-buffered
// 2-phase pipeline (unchanged from round 5).
// ---------------------------------------------------------------------------
__global__ __launch_bounds__(256) void moe_gemm_kernel(
    const __hip_bfloat16* __restrict__ xbf, const __hip_bfloat16* __restrict__ Wt,
    const float* __restrict__ bias,
    const int* __restrict__ counts, const int* __restrict__ rowlist,
    const float* __restrict__ gatelist, float* __restrict__ out, float* __restrict__ out2)
{
    const int nt = blockIdx.x;
    const int e  = blockIdx.y;
    const int mt = blockIdx.z;
    const int cnt  = counts[e];
    const int row0 = mt * 128;
    if (row0 >= cnt) return;

    __shared__ int   srow[128];
    __shared__ unsigned char srank[128];
    __shared__ float sgate[128];
    __shared__ __align__(16) unsigned char Alds[2][128 * 128];  // [buf][row][64 bf16]
    __shared__ __align__(16) unsigned char Blds[2][128 * 128];  // [buf][n][64 bf16]

    const int t = threadIdx.x;
    if (t < 128) {
        const int r = row0 + t;
        const unsigned er = (r < cnt) ? (unsigned)rowlist[e * B_ROWS + r] : 0u;
        srow[t]  = (int)(er & 0x7fffffffu);
        srank[t] = (unsigned char)(er >> 31);
        sgate[t] = (r < cnt) ? gatelist[e * B_ROWS + r] : 0.0f;
    }
    __syncthreads();

    const int wave = t >> 6, lane = t & 63;
    const int wr = wave >> 1, wc = wave & 1;
    const int l4 = lane >> 4, l16 = lane & 15;
    const int lrow  = lane >> 3;            // 0..7: row within 8-row stripe
    const int lchunk = (lane & 7) ^ lrow;   // inverse swizzle: slot s holds chunk s^row

    // per-lane byte source bases (constant over kt)
    const char* asrc[4]; const char* bsrc[4];
#pragma unroll
    for (int i = 0; i < 4; ++i) {
        const int r  = wave * 32 + i * 8 + lrow;
        asrc[i] = (const char*)xbf + 2 * ((size_t)srow[r] * DDIM + lchunk * 8);
        const int gn = nt * 128 + wave * 32 + i * 8 + lrow;
        bsrc[i] = (const char*)Wt  + 2 * ((size_t)e * DDIM * DDIM + (size_t)gn * DDIM + lchunk * 8);
    }

    f32x4 acc[4][4];
#pragma unroll
    for (int m = 0; m < 4; ++m)
#pragma unroll
        for (int n = 0; n < 4; ++n) acc[m][n] = (f32x4){0.f, 0.f, 0.f, 0.f};

#define STAGE(bufi, koff)                                                      \
    {                                                                          \
        _Pragma("unroll")                                                      \
        for (int i = 0; i < 4; ++i) {                                          \
            GLOAD_LDS16(asrc[i] + (koff), Alds[bufi] + (wave * 32 + i * 8) * 128); \
            GLOAD_LDS16(bsrc[i] + (koff), Blds[bufi] + (wave * 32 + i * 8) * 128); \
        }                                                                      \
    }

    // prologue: stage tile 0, wait, barrier
    STAGE(0, 0)
    asm volatile("s_waitcnt vmcnt(0)" ::: "memory");
    __builtin_amdgcn_s_barrier();

    int cur = 0;
    for (int kt = 0; kt < DDIM / 64; ++kt) {
        // issue next-tile loads first (latency hidden under compute below)
        if (kt < DDIM / 64 - 1) STAGE(cur ^ 1, (kt + 1) * 128)

        // compute on buf[cur]
#pragma unroll
        for (int ks = 0; ks < 2; ++ks) {
            bf16x8 af[4], bfr[4];
#pragma unroll
            for (int m = 0; m < 4; ++m) {
                const int row = wr * 64 + m * 16 + l16;
                af[m] = *(const bf16x8*)(Alds[cur] + row * 128 + ((ks * 64 + l4 * 16) ^ ((row & 7) << 4)));
            }
#pragma unroll
            for (int n = 0; n < 4; ++n) {
                const int rn = wc * 64 + n * 16 + l16;
                bfr[n] = *(const bf16x8*)(Blds[cur] + rn * 128 + ((ks * 64 + l4 * 16) ^ ((rn & 7) << 4)));
            }
#pragma unroll
            for (int m = 0; m < 4; ++m)
#pragma unroll
                for (int n = 0; n < 4; ++n)
                    acc[m][n] = __builtin_amdgcn_mfma_f32_16x16x32_bf16(af[m], bfr[n], acc[m][n], 0, 0, 0);
        }

        // next-tile loads done (mine), then everyone's
        asm volatile("s_waitcnt vmcnt(0)" ::: "memory");
        __builtin_amdgcn_s_barrier();
        cur ^= 1;
    }
#undef STAGE

    // ---- epilogue: dst[b,h] = g * exp(acc + bias), dst = rank ? out2 : out ----
#pragma unroll
    for (int m = 0; m < 4; ++m) {
#pragma unroll
        for (int n = 0; n < 4; ++n) {
#pragma unroll
            for (int j = 0; j < 4; ++j) {
                const int R = wr * 64 + m * 16 + l4 * 4 + j;   // C/D: row=(l>>4)*4+j, col=l&15
                if (row0 + R < cnt) {
                    const int   brow = srow[R];
                    const float g    = sgate[R];
                    const int   h    = nt * 128 + wc * 64 + n * 16 + l16;
                    const float v    = g * __expf(acc[m][n][j] + bias[e * DDIM + h]);
                    float* dst = srank[R] ? out2 : out;
                    dst[(size_t)brow * DDIM + h] = v;
                }
            }
        }
    }
}

// ---------------------------------------------------------------------------
// Kernel 3: out = log(out + out2), 0 -> EPS
// ---------------------------------------------------------------------------
__global__ __launch_bounds__(256) void logeps_kernel(
    float* __restrict__ o, const float* __restrict__ o2, int n4)
{
    const float EPSF = 2.220446049250313e-16f;  // np.finfo(float64).eps
    int i = blockIdx.x * blockDim.x + threadIdx.x;
    const int stride = gridDim.x * blockDim.x;
    float4* p = (float4*)o;
    const float4* q = (const float4*)o2;
    for (; i < n4; i += stride) {
        float4 a = p[i];
        const float4 b = q[i];
        a.x += b.x; a.y += b.y; a.z += b.z; a.w += b.w;
        a.x = __logf(a.x == 0.0f ? EPSF : a.x);
        a.y = __logf(a.y == 0.0f ? EPSF : a.y);
        a.z = __logf(a.z == 0.0f ? EPSF : a.z);
        a.w = __logf(a.w == 0.0f ? EPSF : a.w);
        p[i] = a;
    }
}

// ---------------------------------------------------------------------------
extern "C" void kernel_launch(void* const* d_in, const int* in_sizes, int n_in,
                              void* d_out, int out_size, void* d_ws, size_t ws_size,
                              hipStream_t stream)
{
    const float* x       = (const float*)d_in[0];
    const float* noise   = (const float*)d_in[1];
    const float* w_gate  = (const float*)d_in[2];
    const float* w_noise = (const float*)d_in[3];
    const float* W       = (const float*)d_in[4];
    const float* bias    = (const float*)d_in[5];
    float* out = (float*)d_out;

    char* ws = (char*)d_ws;
    int*   counts   = (int*)ws;                                    // 64 B
    float* wt       = (float*)(ws + 256);                          // 64 KB
    int*   rowlist  = (int*)(ws + 256 + 65536);                    // 256 KB
    float* gatelist = (float*)(ws + 256 + 65536 + NEXP * B_ROWS * 4);
    __hip_bfloat16* xbf = (__hip_bfloat16*)(ws + (1u << 20));                  // 16 MB
    __hip_bfloat16* Wt  = (__hip_bfloat16*)(ws + (1u << 20) + (16u << 20));    // 16 MB
    float* out2 = (float*)(ws + (1u << 20) + (32u << 20));                     // 32 MB

    hipMemsetAsync(counts, 0, 64, stream);

    wprep_kernel<<<64, 256, 0, stream>>>(w_gate, w_noise, wt);
    gating_kernel<<<B_ROWS / 4, 256, 0, stream>>>(x, noise, wt,
                                                  counts, rowlist, gatelist);
    xconv_kernel<<<1024, 256, 0, stream>>>(x, xbf);
    wtrans_kernel<<<dim3(16, 16, NEXP), 256, 0, stream>>>(W, Wt);

    dim3 grid(NEXP /*nt*/, NEXP /*e*/, B_ROWS / 128 /*mt*/);
    moe_gemm_kernel<<<grid, 256, 0, stream>>>(xbf, Wt, bias, counts, rowlist, gatelist,
                                              out, out2);

    logeps_kernel<<<2048, 256, 0, stream>>>(out, out2, out_size / 4);
}

// Round 7
// 381.303 us; speedup vs baseline: 1.2164x; 1.2164x over previous
//
#include <hip/hip_runtime.h>
#include <hip/hip_bf16.h>
#include <math.h>

#define B_ROWS 8192
#define DDIM   1024
#define NEXP   8

typedef __attribute__((ext_vector_type(8))) __bf16 bf16x8;
typedef __attribute__((ext_vector_type(4))) float  f32x4;

__device__ __forceinline__ unsigned short f2bf(float f) {
    // round-to-nearest-even f32 -> bf16
    unsigned u = __builtin_bit_cast(unsigned, f);
    u = (u + 0x7fffu + ((u >> 16) & 1u)) >> 16;
    return (unsigned short)u;
}

// async global->LDS, 16B per lane; LDS dest = wave-uniform base + lane*16
#define GLOAD_LDS16(gptr, lptr)                                                \
    __builtin_amdgcn_global_load_lds(                                          \
        (const __attribute__((address_space(1))) unsigned int*)(gptr),         \
        (__attribute__((address_space(3))) unsigned int*)(lptr), 16, 0, 0)

// ---------------------------------------------------------------------------
// Pre-pass A: x (f32) -> xbf (bf16), 8M elements.
// ---------------------------------------------------------------------------
__global__ __launch_bounds__(256) void xconv_kernel(
    const float* __restrict__ x, __hip_bfloat16* __restrict__ xbf)
{
    int i = blockIdx.x * 256 + threadIdx.x;
    const int stride = gridDim.x * 256;
    const int n8 = B_ROWS * DDIM / 8;
    for (; i < n8; i += stride) {
        const float4 f0 = *(const float4*)(x + (size_t)i * 8);
        const float4 f1 = *(const float4*)(x + (size_t)i * 8 + 4);
        union { bf16x8 v; unsigned short u[8]; } pk;
        pk.u[0] = f2bf(f0.x); pk.u[1] = f2bf(f0.y); pk.u[2] = f2bf(f0.z); pk.u[3] = f2bf(f0.w);
        pk.u[4] = f2bf(f1.x); pk.u[5] = f2bf(f1.y); pk.u[6] = f2bf(f1.z); pk.u[7] = f2bf(f1.w);
        *(bf16x8*)((__hip_bfloat16*)xbf + (size_t)i * 8) = pk.v;
    }
}

// ---------------------------------------------------------------------------
// Pre-pass B: W [e][k][n] f32 -> Wt [e][n][k] bf16 via 64x64 LDS tile.
// ---------------------------------------------------------------------------
__global__ __launch_bounds__(256) void wtrans_kernel(
    const float* __restrict__ W, __hip_bfloat16* __restrict__ Wt)
{
    const int e  = blockIdx.z;
    const int k0 = blockIdx.y * 64;
    const int n0 = blockIdx.x * 64;
    __shared__ float st[64][65];          // +1 pad

    const int t = threadIdx.x;
    {
        const int kk = t >> 4;
        const int nn = (t & 15) * 4;
#pragma unroll
        for (int p = 0; p < 4; ++p) {
            const int k = p * 16 + kk;
            const float4 v = *(const float4*)(W + (size_t)e * DDIM * DDIM
                                                + (size_t)(k0 + k) * DDIM + n0 + nn);
            st[k][nn + 0] = v.x; st[k][nn + 1] = v.y;
            st[k][nn + 2] = v.z; st[k][nn + 3] = v.w;
        }
    }
    __syncthreads();
    {
        const int wave = t >> 6, lane = t & 63;
        const int nr = lane >> 3, kc = lane & 7;
#pragma unroll
        for (int p = 0; p < 2; ++p) {
            const int n = p * 32 + wave * 8 + nr;
            union { bf16x8 v; unsigned short u[8]; } pk;
#pragma unroll
            for (int j = 0; j < 8; ++j) pk.u[j] = f2bf(st[kc * 8 + j][n]);
            *(bf16x8*)((__hip_bfloat16*)Wt + (size_t)e * DDIM * DDIM
                        + (size_t)(n0 + n) * DDIM + k0 + kc * 8) = pk.v;
        }
    }
}

// ---------------------------------------------------------------------------
// Pre-pass C: replicated gate-weight layout for coalesced gating loads:
// wtr[K8][c][j] = col_c[K8*8+j], K8 = k-octet 0..127, c: 0-7 w_gate col,
// 8-15 w_noise col. 64KB. Lane group {c=0..15} then reads one contiguous
// 512B segment per K8 -> fully coalesced (fixes v5's 4KB-stride gather).
// ---------------------------------------------------------------------------
__global__ __launch_bounds__(256) void wprep_kernel(
    const float* __restrict__ wg, const float* __restrict__ wn, float* __restrict__ wtr)
{
    const int idx = blockIdx.x * 256 + threadIdx.x;   // 0..16383
    if (idx < 16 * DDIM) {
        const int k8  = idx >> 7;          // K8
        const int rem = idx & 127;
        const int c   = rem >> 3;
        const int j   = rem & 7;
        const int k   = k8 * 8 + j;
        wtr[idx] = (c < 8) ? wg[k * NEXP + c] : wn[k * NEXP + (c - 8)];
    }
}

// ---------------------------------------------------------------------------
// Kernel 1: gating v6 — coalesced wt via replicated layout.
// Wave = 2 rows. Lane = (ks=bit5, rs=bit4, c=bits0-3): lane accumulates the
// 512-element K-slice ks of logit column c for row rs, 8 independent f64
// accumulators (f32 products -> selection matches f64 numpy reference).
// wt loads: 16 c-lanes = contiguous 512B (coalesced), rs broadcast, 2 ks
// segments. ks-halves combined via shfl_xor(32); then verified butterfly
// (8 for noise partner; 1,2,4 for top-2, tie -> lower index).
// rowlist entry = row | (rank<<31).
// ---------------------------------------------------------------------------
__global__ __launch_bounds__(256) void gating_kernel(
    const float* __restrict__ x, const float* __restrict__ noise,
    const float* __restrict__ wtr,
    int* __restrict__ counts, int* __restrict__ rowlist, float* __restrict__ gatelist)
{
    const int t = threadIdx.x;
    const int wave = t >> 6, lane = t & 63;
    const int ks = lane >> 5;          // bit 5
    const int rs = (lane >> 4) & 1;    // bit 4
    const int c  = lane & 15;          // bits 0-3
    const int row = blockIdx.x * 8 + wave * 2 + rs;

    const float* xr = x   + (size_t)row * DDIM + ks * 512;
    const float* wr = wtr + (size_t)ks * 8192 + c * 8;   // + k8*128 per iter

    double a0 = 0, a1 = 0, a2 = 0, a3 = 0, a4 = 0, a5 = 0, a6 = 0, a7 = 0;
#pragma unroll 4
    for (int k8 = 0; k8 < 64; ++k8) {
        const float4 xv0 = *(const float4*)(xr + k8 * 8);
        const float4 xv1 = *(const float4*)(xr + k8 * 8 + 4);
        const float4 wv0 = *(const float4*)(wr + k8 * 128);
        const float4 wv1 = *(const float4*)(wr + k8 * 128 + 4);
        a0 += (double)(xv0.x * wv0.x);
        a1 += (double)(xv0.y * wv0.y);
        a2 += (double)(xv0.z * wv0.z);
        a3 += (double)(xv0.w * wv0.w);
        a4 += (double)(xv1.x * wv1.x);
        a5 += (double)(xv1.y * wv1.y);
        a6 += (double)(xv1.z * wv1.z);
        a7 += (double)(xv1.w * wv1.w);
    }
    double acc = ((a0 + a1) + (a2 + a3)) + ((a4 + a5) + (a6 + a7));

    // combine the two ks K-slices (bit 5; same rs,c)
    acc += __shfl_xor(acc, 32);

    const double vnoise = __shfl_xor(acc, 8);     // partner column c^8

    double lgv = -1.0e300;
    if (c < 8) {
        const double z  = vnoise;
        const double sp = (z > 30.0) ? z : log1p(exp(z));
        lgv = acc + (double)noise[(size_t)row * NEXP + c] * (sp + 0.01);
    }

    // top-1 butterfly over the 8 logit lanes (offsets 1,2,4; closed per rs,ks)
    double bv = lgv; int bi = c;
#pragma unroll
    for (int off = 1; off <= 4; off <<= 1) {
        const double ov = __shfl_xor(bv, off);
        const int    oi = __shfl_xor(bi, off);
        if (ov > bv || (ov == bv && oi < bi)) { bv = ov; bi = oi; }
    }
    // top-2: mask winner, reduce again
    double b2v = (c == bi) ? -1.0e300 : lgv; int b2i = c;
#pragma unroll
    for (int off = 1; off <= 4; off <<= 1) {
        const double ov = __shfl_xor(b2v, off);
        const int    oi = __shfl_xor(b2i, off);
        if (ov > b2v || (ov == b2v && oi < b2i)) { b2v = ov; b2i = oi; }
    }

    if ((lane & 47) == 0) {   // c==0 && ks==0  -> lanes 0 (rs0) and 16 (rs1)
        const double g0 = 1.0 / (1.0 + exp(b2v - bv));
        const double g1 = 1.0 - g0;
        int p0 = atomicAdd(&counts[bi], 1);
        rowlist [bi * B_ROWS + p0] = row;                                 // rank 0
        gatelist[bi * B_ROWS + p0] = (float)g0;
        int p1 = atomicAdd(&counts[b2i], 1);
        rowlist [b2i * B_ROWS + p1] = (int)((unsigned)row | 0x80000000u); // rank 1
        gatelist[b2i * B_ROWS + p1] = (float)g1;
    }
}

// ---------------------------------------------------------------------------
// Kernel 2: grouped expert GEMM, 128x128 tile, BK=64, double-buffered
// 2-phase pipeline (unchanged).
// ---------------------------------------------------------------------------
__global__ __launch_bounds__(256) void moe_gemm_kernel(
    const __hip_bfloat16* __restrict__ xbf, const __hip_bfloat16* __restrict__ Wt,
    const float* __restrict__ bias,
    const int* __restrict__ counts, const int* __restrict__ rowlist,
    const float* __restrict__ gatelist, float* __restrict__ out, float* __restrict__ out2)
{
    const int nt = blockIdx.x;
    const int e  = blockIdx.y;
    const int mt = blockIdx.z;
    const int cnt  = counts[e];
    const int row0 = mt * 128;
    if (row0 >= cnt) return;

    __shared__ int   srow[128];
    __shared__ unsigned char srank[128];
    __shared__ float sgate[128];
    __shared__ __align__(16) unsigned char Alds[2][128 * 128];  // [buf][row][64 bf16]
    __shared__ __align__(16) unsigned char Blds[2][128 * 128];  // [buf][n][64 bf16]

    const int t = threadIdx.x;
    if (t < 128) {
        const int r = row0 + t;
        const unsigned er = (r < cnt) ? (unsigned)rowlist[e * B_ROWS + r] : 0u;
        srow[t]  = (int)(er & 0x7fffffffu);
        srank[t] = (unsigned char)(er >> 31);
        sgate[t] = (r < cnt) ? gatelist[e * B_ROWS + r] : 0.0f;
    }
    __syncthreads();

    const int wave = t >> 6, lane = t & 63;
    const int wr = wave >> 1, wc = wave & 1;
    const int l4 = lane >> 4, l16 = lane & 15;
    const int lrow  = lane >> 3;            // 0..7: row within 8-row stripe
    const int lchunk = (lane & 7) ^ lrow;   // inverse swizzle: slot s holds chunk s^row

    // per-lane byte source bases (constant over kt)
    const char* asrc[4]; const char* bsrc[4];
#pragma unroll
    for (int i = 0; i < 4; ++i) {
        const int r  = wave * 32 + i * 8 + lrow;
        asrc[i] = (const char*)xbf + 2 * ((size_t)srow[r] * DDIM + lchunk * 8);
        const int gn = nt * 128 + wave * 32 + i * 8 + lrow;
        bsrc[i] = (const char*)Wt  + 2 * ((size_t)e * DDIM * DDIM + (size_t)gn * DDIM + lchunk * 8);
    }

    f32x4 acc[4][4];
#pragma unroll
    for (int m = 0; m < 4; ++m)
#pragma unroll
        for (int n = 0; n < 4; ++n) acc[m][n] = (f32x4){0.f, 0.f, 0.f, 0.f};

#define STAGE(bufi, koff)                                                      \
    {                                                                          \
        _Pragma("unroll")                                                      \
        for (int i = 0; i < 4; ++i) {                                          \
            GLOAD_LDS16(asrc[i] + (koff), Alds[bufi] + (wave * 32 + i * 8) * 128); \
            GLOAD_LDS16(bsrc[i] + (koff), Blds[bufi] + (wave * 32 + i * 8) * 128); \
        }                                                                      \
    }

    // prologue: stage tile 0, wait, barrier
    STAGE(0, 0)
    asm volatile("s_waitcnt vmcnt(0)" ::: "memory");
    __builtin_amdgcn_s_barrier();

    int cur = 0;
    for (int kt = 0; kt < DDIM / 64; ++kt) {
        // issue next-tile loads first (latency hidden under compute below)
        if (kt < DDIM / 64 - 1) STAGE(cur ^ 1, (kt + 1) * 128)

        // compute on buf[cur]
#pragma unroll
        for (int ks = 0; ks < 2; ++ks) {
            bf16x8 af[4], bfr[4];
#pragma unroll
            for (int m = 0; m < 4; ++m) {
                const int row = wr * 64 + m * 16 + l16;
                af[m] = *(const bf16x8*)(Alds[cur] + row * 128 + ((ks * 64 + l4 * 16) ^ ((row & 7) << 4)));
            }
#pragma unroll
            for (int n = 0; n < 4; ++n) {
                const int rn = wc * 64 + n * 16 + l16;
                bfr[n] = *(const bf16x8*)(Blds[cur] + rn * 128 + ((ks * 64 + l4 * 16) ^ ((rn & 7) << 4)));
            }
#pragma unroll
            for (int m = 0; m < 4; ++m)
#pragma unroll
                for (int n = 0; n < 4; ++n)
                    acc[m][n] = __builtin_amdgcn_mfma_f32_16x16x32_bf16(af[m], bfr[n], acc[m][n], 0, 0, 0);
        }

        // next-tile loads done (mine), then everyone's
        asm volatile("s_waitcnt vmcnt(0)" ::: "memory");
        __builtin_amdgcn_s_barrier();
        cur ^= 1;
    }
#undef STAGE

    // ---- epilogue: dst[b,h] = g * exp(acc + bias), dst = rank ? out2 : out ----
#pragma unroll
    for (int m = 0; m < 4; ++m) {
#pragma unroll
        for (int n = 0; n < 4; ++n) {
#pragma unroll
            for (int j = 0; j < 4; ++j) {
                const int R = wr * 64 + m * 16 + l4 * 4 + j;   // C/D: row=(l>>4)*4+j, col=l&15
                if (row0 + R < cnt) {
                    const int   brow = srow[R];
                    const float g    = sgate[R];
                    const int   h    = nt * 128 + wc * 64 + n * 16 + l16;
                    const float v    = g * __expf(acc[m][n][j] + bias[e * DDIM + h]);
                    float* dst = srank[R] ? out2 : out;
                    dst[(size_t)brow * DDIM + h] = v;
                }
            }
        }
    }
}

// ---------------------------------------------------------------------------
// Kernel 3: out = log(out + out2), 0 -> EPS
// ---------------------------------------------------------------------------
__global__ __launch_bounds__(256) void logeps_kernel(
    float* __restrict__ o, const float* __restrict__ o2, int n4)
{
    const float EPSF = 2.220446049250313e-16f;  // np.finfo(float64).eps
    int i = blockIdx.x * blockDim.x + threadIdx.x;
    const int stride = gridDim.x * blockDim.x;
    float4* p = (float4*)o;
    const float4* q = (const float4*)o2;
    for (; i < n4; i += stride) {
        float4 a = p[i];
        const float4 b = q[i];
        a.x += b.x; a.y += b.y; a.z += b.z; a.w += b.w;
        a.x = __logf(a.x == 0.0f ? EPSF : a.x);
        a.y = __logf(a.y == 0.0f ? EPSF : a.y);
        a.z = __logf(a.z == 0.0f ? EPSF : a.z);
        a.w = __logf(a.w == 0.0f ? EPSF : a.w);
        p[i] = a;
    }
}

// ---------------------------------------------------------------------------
extern "C" void kernel_launch(void* const* d_in, const int* in_sizes, int n_in,
                              void* d_out, int out_size, void* d_ws, size_t ws_size,
                              hipStream_t stream)
{
    const float* x       = (const float*)d_in[0];
    const float* noise   = (const float*)d_in[1];
    const float* w_gate  = (const float*)d_in[2];
    const float* w_noise = (const float*)d_in[3];
    const float* W       = (const float*)d_in[4];
    const float* bias    = (const float*)d_in[5];
    float* out = (float*)d_out;

    char* ws = (char*)d_ws;
    int*   counts   = (int*)ws;                                    // 64 B
    float* wtr      = (float*)(ws + 256);                          // 64 KB
    int*   rowlist  = (int*)(ws + 256 + 65536);                    // 256 KB
    float* gatelist = (float*)(ws + 256 + 65536 + NEXP * B_ROWS * 4);
    __hip_bfloat16* xbf = (__hip_bfloat16*)(ws + (1u << 20));                  // 16 MB
    __hip_bfloat16* Wt  = (__hip_bfloat16*)(ws + (1u << 20) + (16u << 20));    // 16 MB
    float* out2 = (float*)(ws + (1u << 20) + (32u << 20));                     // 32 MB

    hipMemsetAsync(counts, 0, 64, stream);

    wprep_kernel<<<64, 256, 0, stream>>>(w_gate, w_noise, wtr);
    gating_kernel<<<B_ROWS / 8, 256, 0, stream>>>(x, noise, wtr,
                                                  counts, rowlist, gatelist);
    xconv_kernel<<<1024, 256, 0, stream>>>(x, xbf);
    wtrans_kernel<<<dim3(16, 16, NEXP), 256, 0, stream>>>(W, Wt);

    dim3 grid(NEXP /*nt*/, NEXP /*e*/, B_ROWS / 128 /*mt*/);
    moe_gemm_kernel<<<grid, 256, 0, stream>>>(xbf, Wt, bias, counts, rowlist, gatelist,
                                              out, out2);

    logeps_kernel<<<2048, 256, 0, stream>>>(out, out2, out_size / 4);
}

// Round 8
// 364.838 us; speedup vs baseline: 1.2713x; 1.0451x over previous
//
#include <hip/hip_runtime.h>
#include <hip/hip_bf16.h>
#include <math.h>

#define B_ROWS 8192
#define DDIM   1024
#define NEXP   8

typedef __attribute__((ext_vector_type(8))) __bf16 bf16x8;
typedef __attribute__((ext_vector_type(4))) float  f32x4;

__device__ __forceinline__ unsigned short f2bf(float f) {
    // round-to-nearest-even f32 -> bf16
    unsigned u = __builtin_bit_cast(unsigned, f);
    u = (u + 0x7fffu + ((u >> 16) & 1u)) >> 16;
    return (unsigned short)u;
}

// async global->LDS, 16B per lane; LDS dest = wave-uniform base + lane*16
#define GLOAD_LDS16(gptr, lptr)                                                \
    __builtin_amdgcn_global_load_lds(                                          \
        (const __attribute__((address_space(1))) unsigned int*)(gptr),         \
        (__attribute__((address_space(3))) unsigned int*)(lptr), 16, 0, 0)

// ---------------------------------------------------------------------------
// Pre-pass A: x (f32) -> xbf (bf16), 8M elements.
// ---------------------------------------------------------------------------
__global__ __launch_bounds__(256) void xconv_kernel(
    const float* __restrict__ x, __hip_bfloat16* __restrict__ xbf)
{
    int i = blockIdx.x * 256 + threadIdx.x;
    const int stride = gridDim.x * 256;
    const int n8 = B_ROWS * DDIM / 8;
    for (; i < n8; i += stride) {
        const float4 f0 = *(const float4*)(x + (size_t)i * 8);
        const float4 f1 = *(const float4*)(x + (size_t)i * 8 + 4);
        union { bf16x8 v; unsigned short u[8]; } pk;
        pk.u[0] = f2bf(f0.x); pk.u[1] = f2bf(f0.y); pk.u[2] = f2bf(f0.z); pk.u[3] = f2bf(f0.w);
        pk.u[4] = f2bf(f1.x); pk.u[5] = f2bf(f1.y); pk.u[6] = f2bf(f1.z); pk.u[7] = f2bf(f1.w);
        *(bf16x8*)((__hip_bfloat16*)xbf + (size_t)i * 8) = pk.v;
    }
}

// ---------------------------------------------------------------------------
// Pre-pass B: W [e][k][n] f32 -> Wt [e][n][k] bf16 via 64x64 LDS tile.
// ---------------------------------------------------------------------------
__global__ __launch_bounds__(256) void wtrans_kernel(
    const float* __restrict__ W, __hip_bfloat16* __restrict__ Wt)
{
    const int e  = blockIdx.z;
    const int k0 = blockIdx.y * 64;
    const int n0 = blockIdx.x * 64;
    __shared__ float st[64][65];          // +1 pad

    const int t = threadIdx.x;
    {
        const int kk = t >> 4;
        const int nn = (t & 15) * 4;
#pragma unroll
        for (int p = 0; p < 4; ++p) {
            const int k = p * 16 + kk;
            const float4 v = *(const float4*)(W + (size_t)e * DDIM * DDIM
                                                + (size_t)(k0 + k) * DDIM + n0 + nn);
            st[k][nn + 0] = v.x; st[k][nn + 1] = v.y;
            st[k][nn + 2] = v.z; st[k][nn + 3] = v.w;
        }
    }
    __syncthreads();
    {
        const int wave = t >> 6, lane = t & 63;
        const int nr = lane >> 3, kc = lane & 7;
#pragma unroll
        for (int p = 0; p < 2; ++p) {
            const int n = p * 32 + wave * 8 + nr;
            union { bf16x8 v; unsigned short u[8]; } pk;
#pragma unroll
            for (int j = 0; j < 8; ++j) pk.u[j] = f2bf(st[kc * 8 + j][n]);
            *(bf16x8*)((__hip_bfloat16*)Wt + (size_t)e * DDIM * DDIM
                        + (size_t)(n0 + n) * DDIM + k0 + kc * 8) = pk.v;
        }
    }
}

// ---------------------------------------------------------------------------
// Pre-pass C: replicated gate-weight layout: wtr[K8][c][j] = col_c[K8*8+j].
// 16 c-lanes read one contiguous 512B segment per K8 -> coalesced.
// ---------------------------------------------------------------------------
__global__ __launch_bounds__(256) void wprep_kernel(
    const float* __restrict__ wg, const float* __restrict__ wn, float* __restrict__ wtr)
{
    const int idx = blockIdx.x * 256 + threadIdx.x;   // 0..16383
    if (idx < 16 * DDIM) {
        const int k8  = idx >> 7;
        const int rem = idx & 127;
        const int c   = rem >> 3;
        const int j   = rem & 7;
        const int k   = k8 * 8 + j;
        wtr[idx] = (c < 8) ? wg[k * NEXP + c] : wn[k * NEXP + (c - 8)];
    }
}

// ---------------------------------------------------------------------------
// Kernel 1: gating v7 — v6 math, BATCHED loads. 16 outer iterations; each
// fills xb[8]/wb[8] (16 independent float4 loads, static indices -> regs)
// then runs 32 FMAs. Latency exposed once per outer iter instead of per
// octet (v6's VGPR=36 showed the compiler serialized load->use per octet).
// Accumulator mapping and order identical to v6 -> bitwise-same f64 logits
// -> identical top-k selection vs the f64 numpy reference.
// ---------------------------------------------------------------------------
__global__ __launch_bounds__(256) void gating_kernel(
    const float* __restrict__ x, const float* __restrict__ noise,
    const float* __restrict__ wtr,
    int* __restrict__ counts, int* __restrict__ rowlist, float* __restrict__ gatelist)
{
    const int t = threadIdx.x;
    const int wave = t >> 6, lane = t & 63;
    const int ks = lane >> 5;          // bit 5
    const int rs = (lane >> 4) & 1;    // bit 4
    const int c  = lane & 15;          // bits 0-3
    const int row = blockIdx.x * 8 + wave * 2 + rs;

    const float* xr = x   + (size_t)row * DDIM + ks * 512;
    const float* wr = wtr + (size_t)ks * 8192 + c * 8;   // + k8*128 per octet

    double a0 = 0, a1 = 0, a2 = 0, a3 = 0, a4 = 0, a5 = 0, a6 = 0, a7 = 0;
    for (int ko = 0; ko < 16; ++ko) {            // 4 K8-octets per outer iter
        float4 xb[8], wb[8];
#pragma unroll
        for (int i = 0; i < 4; ++i) {
            const int k8 = ko * 4 + i;
            xb[2 * i]     = *(const float4*)(xr + k8 * 8);
            xb[2 * i + 1] = *(const float4*)(xr + k8 * 8 + 4);
            wb[2 * i]     = *(const float4*)(wr + k8 * 128);
            wb[2 * i + 1] = *(const float4*)(wr + k8 * 128 + 4);
        }
#pragma unroll
        for (int i = 0; i < 4; ++i) {
            a0 += (double)(xb[2 * i].x     * wb[2 * i].x);
            a1 += (double)(xb[2 * i].y     * wb[2 * i].y);
            a2 += (double)(xb[2 * i].z     * wb[2 * i].z);
            a3 += (double)(xb[2 * i].w     * wb[2 * i].w);
            a4 += (double)(xb[2 * i + 1].x * wb[2 * i + 1].x);
            a5 += (double)(xb[2 * i + 1].y * wb[2 * i + 1].y);
            a6 += (double)(xb[2 * i + 1].z * wb[2 * i + 1].z);
            a7 += (double)(xb[2 * i + 1].w * wb[2 * i + 1].w);
        }
    }
    double acc = ((a0 + a1) + (a2 + a3)) + ((a4 + a5) + (a6 + a7));

    // combine the two ks K-slices (bit 5; same rs,c)
    acc += __shfl_xor(acc, 32);

    const double vnoise = __shfl_xor(acc, 8);     // partner column c^8

    double lgv = -1.0e300;
    if (c < 8) {
        const double z  = vnoise;
        const double sp = (z > 30.0) ? z : log1p(exp(z));
        lgv = acc + (double)noise[(size_t)row * NEXP + c] * (sp + 0.01);
    }

    // top-1 butterfly over the 8 logit lanes (offsets 1,2,4; closed per rs,ks)
    double bv = lgv; int bi = c;
#pragma unroll
    for (int off = 1; off <= 4; off <<= 1) {
        const double ov = __shfl_xor(bv, off);
        const int    oi = __shfl_xor(bi, off);
        if (ov > bv || (ov == bv && oi < bi)) { bv = ov; bi = oi; }
    }
    // top-2: mask winner, reduce again
    double b2v = (c == bi) ? -1.0e300 : lgv; int b2i = c;
#pragma unroll
    for (int off = 1; off <= 4; off <<= 1) {
        const double ov = __shfl_xor(b2v, off);
        const int    oi = __shfl_xor(b2i, off);
        if (ov > b2v || (ov == b2v && oi < b2i)) { b2v = ov; b2i = oi; }
    }

    if ((lane & 47) == 0) {   // c==0 && ks==0 -> lanes 0 (rs0) and 16 (rs1)
        const double g0 = 1.0 / (1.0 + exp(b2v - bv));
        const double g1 = 1.0 - g0;
        int p0 = atomicAdd(&counts[bi], 1);
        rowlist [bi * B_ROWS + p0] = row;                                 // rank 0
        gatelist[bi * B_ROWS + p0] = (float)g0;
        int p1 = atomicAdd(&counts[b2i], 1);
        rowlist [b2i * B_ROWS + p1] = (int)((unsigned)row | 0x80000000u); // rank 1
        gatelist[b2i * B_ROWS + p1] = (float)g1;
    }
}

// ---------------------------------------------------------------------------
// Kernel 2: grouped expert GEMM, 128x128 tile, BK=64, SINGLE-buffer m97
// structure (dbuf reverted: no measured gain, and 66KB LDS halved occupancy).
// Grid = (nt, e, mt) so the resident id-window is fully active.
// Epilogue: rank0 rows -> out, rank1 rows -> out2 (atomic-free).
// ---------------------------------------------------------------------------
__global__ __launch_bounds__(256) void moe_gemm_kernel(
    const __hip_bfloat16* __restrict__ xbf, const __hip_bfloat16* __restrict__ Wt,
    const float* __restrict__ bias,
    const int* __restrict__ counts, const int* __restrict__ rowlist,
    const float* __restrict__ gatelist, float* __restrict__ out, float* __restrict__ out2)
{
    const int nt = blockIdx.x;
    const int e  = blockIdx.y;
    const int mt = blockIdx.z;
    const int cnt  = counts[e];
    const int row0 = mt * 128;
    if (row0 >= cnt) return;

    __shared__ int   srow[128];
    __shared__ unsigned char srank[128];
    __shared__ float sgate[128];
    __shared__ __align__(16) unsigned char Alds[128 * 128];  // [row][64 bf16]
    __shared__ __align__(16) unsigned char Blds[128 * 128];  // [n][64 bf16]

    const int t = threadIdx.x;
    if (t < 128) {
        const int r = row0 + t;
        const unsigned er = (r < cnt) ? (unsigned)rowlist[e * B_ROWS + r] : 0u;
        srow[t]  = (int)(er & 0x7fffffffu);
        srank[t] = (unsigned char)(er >> 31);
        sgate[t] = (r < cnt) ? gatelist[e * B_ROWS + r] : 0.0f;
    }
    __syncthreads();

    const int wave = t >> 6, lane = t & 63;
    const int wr = wave >> 1, wc = wave & 1;
    const int l4 = lane >> 4, l16 = lane & 15;
    const int lrow  = lane >> 3;            // 0..7: row within 8-row stripe
    const int lchunk = (lane & 7) ^ lrow;   // inverse swizzle: slot s holds chunk s^row

    // per-lane byte source bases (constant over kt)
    const char* asrc[4]; const char* bsrc[4];
#pragma unroll
    for (int i = 0; i < 4; ++i) {
        const int r  = wave * 32 + i * 8 + lrow;
        asrc[i] = (const char*)xbf + 2 * ((size_t)srow[r] * DDIM + lchunk * 8);
        const int gn = nt * 128 + wave * 32 + i * 8 + lrow;
        bsrc[i] = (const char*)Wt  + 2 * ((size_t)e * DDIM * DDIM + (size_t)gn * DDIM + lchunk * 8);
    }

    f32x4 acc[4][4];
#pragma unroll
    for (int m = 0; m < 4; ++m)
#pragma unroll
        for (int n = 0; n < 4; ++n) acc[m][n] = (f32x4){0.f, 0.f, 0.f, 0.f};

    for (int kt = 0; kt < DDIM / 64; ++kt) {
        const int koff = kt * 128;  // bytes
#pragma unroll
        for (int i = 0; i < 4; ++i) {
            GLOAD_LDS16(asrc[i] + koff, Alds + (wave * 32 + i * 8) * 128);
            GLOAD_LDS16(bsrc[i] + koff, Blds + (wave * 32 + i * 8) * 128);
        }
        asm volatile("s_waitcnt vmcnt(0)" ::: "memory");
        __syncthreads();

#pragma unroll
        for (int ks = 0; ks < 2; ++ks) {
            bf16x8 af[4], bfr[4];
#pragma unroll
            for (int m = 0; m < 4; ++m) {
                const int row = wr * 64 + m * 16 + l16;
                af[m] = *(const bf16x8*)(Alds + row * 128 + ((ks * 64 + l4 * 16) ^ ((row & 7) << 4)));
            }
#pragma unroll
            for (int n = 0; n < 4; ++n) {
                const int rn = wc * 64 + n * 16 + l16;
                bfr[n] = *(const bf16x8*)(Blds + rn * 128 + ((ks * 64 + l4 * 16) ^ ((rn & 7) << 4)));
            }
#pragma unroll
            for (int m = 0; m < 4; ++m)
#pragma unroll
                for (int n = 0; n < 4; ++n)
                    acc[m][n] = __builtin_amdgcn_mfma_f32_16x16x32_bf16(af[m], bfr[n], acc[m][n], 0, 0, 0);
        }
        __syncthreads();
    }

    // ---- epilogue: dst[b,h] = g * exp(acc + bias), dst = rank ? out2 : out ----
#pragma unroll
    for (int m = 0; m < 4; ++m) {
#pragma unroll
        for (int n = 0; n < 4; ++n) {
#pragma unroll
            for (int j = 0; j < 4; ++j) {
                const int R = wr * 64 + m * 16 + l4 * 4 + j;   // C/D: row=(l>>4)*4+j, col=l&15
                if (row0 + R < cnt) {
                    const int   brow = srow[R];
                    const float g    = sgate[R];
                    const int   h    = nt * 128 + wc * 64 + n * 16 + l16;
                    const float v    = g * __expf(acc[m][n][j] + bias[e * DDIM + h]);
                    float* dst = srank[R] ? out2 : out;
                    dst[(size_t)brow * DDIM + h] = v;
                }
            }
        }
    }
}

// ---------------------------------------------------------------------------
// Kernel 3: out = log(out + out2), 0 -> EPS
// ---------------------------------------------------------------------------
__global__ __launch_bounds__(256) void logeps_kernel(
    float* __restrict__ o, const float* __restrict__ o2, int n4)
{
    const float EPSF = 2.220446049250313e-16f;  // np.finfo(float64).eps
    int i = blockIdx.x * blockDim.x + threadIdx.x;
    const int stride = gridDim.x * blockDim.x;
    float4* p = (float4*)o;
    const float4* q = (const float4*)o2;
    for (; i < n4; i += stride) {
        float4 a = p[i];
        const float4 b = q[i];
        a.x += b.x; a.y += b.y; a.z += b.z; a.w += b.w;
        a.x = __logf(a.x == 0.0f ? EPSF : a.x);
        a.y = __logf(a.y == 0.0f ? EPSF : a.y);
        a.z = __logf(a.z == 0.0f ? EPSF : a.z);
        a.w = __logf(a.w == 0.0f ? EPSF : a.w);
        p[i] = a;
    }
}

// ---------------------------------------------------------------------------
extern "C" void kernel_launch(void* const* d_in, const int* in_sizes, int n_in,
                              void* d_out, int out_size, void* d_ws, size_t ws_size,
                              hipStream_t stream)
{
    const float* x       = (const float*)d_in[0];
    const float* noise   = (const float*)d_in[1];
    const float* w_gate  = (const float*)d_in[2];
    const float* w_noise = (const float*)d_in[3];
    const float* W       = (const float*)d_in[4];
    const float* bias    = (const float*)d_in[5];
    float* out = (float*)d_out;

    char* ws = (char*)d_ws;
    int*   counts   = (int*)ws;                                    // 64 B
    float* wtr      = (float*)(ws + 256);                          // 64 KB
    int*   rowlist  = (int*)(ws + 256 + 65536);                    // 256 KB
    float* gatelist = (float*)(ws + 256 + 65536 + NEXP * B_ROWS * 4);
    __hip_bfloat16* xbf = (__hip_bfloat16*)(ws + (1u << 20));                  // 16 MB
    __hip_bfloat16* Wt  = (__hip_bfloat16*)(ws + (1u << 20) + (16u << 20));    // 16 MB
    float* out2 = (float*)(ws + (1u << 20) + (32u << 20));                     // 32 MB

    hipMemsetAsync(counts, 0, 64, stream);

    wprep_kernel<<<64, 256, 0, stream>>>(w_gate, w_noise, wtr);
    gating_kernel<<<B_ROWS / 8, 256, 0, stream>>>(x, noise, wtr,
                                                  counts, rowlist, gatelist);
    xconv_kernel<<<1024, 256, 0, stream>>>(x, xbf);
    wtrans_kernel<<<dim3(16, 16, NEXP), 256, 0, stream>>>(W, Wt);

    dim3 grid(NEXP /*nt*/, NEXP /*e*/, B_ROWS / 128 /*mt*/);
    moe_gemm_kernel<<<grid, 256, 0, stream>>>(xbf, Wt, bias, counts, rowlist, gatelist,
                                              out, out2);

    logeps_kernel<<<2048, 256, 0, stream>>>(out, out2, out_size / 4);
}

// Round 9
// 345.471 us; speedup vs baseline: 1.3426x; 1.0561x over previous
//
#include <hip/hip_runtime.h>
#include <hip/hip_bf16.h>
#include <math.h>

#define B_ROWS 8192
#define DDIM   1024
#define NEXP   8

typedef __attribute__((ext_vector_type(8))) __bf16 bf16x8;
typedef __attribute__((ext_vector_type(4))) float  f32x4;

__device__ __forceinline__ unsigned short f2bf(float f) {
    // round-to-nearest-even f32 -> bf16
    unsigned u = __builtin_bit_cast(unsigned, f);
    u = (u + 0x7fffu + ((u >> 16) & 1u)) >> 16;
    return (unsigned short)u;
}

// async global->LDS, 16B per lane; LDS dest = wave-uniform base + lane*16
#define GLOAD_LDS16(gptr, lptr)                                                \
    __builtin_amdgcn_global_load_lds(                                          \
        (const __attribute__((address_space(1))) unsigned int*)(gptr),         \
        (__attribute__((address_space(3))) unsigned int*)(lptr), 16, 0, 0)

// ---------------------------------------------------------------------------
// Pre-pass A: x (f32) -> xbf (bf16), 8M elements.
// ---------------------------------------------------------------------------
__global__ __launch_bounds__(256) void xconv_kernel(
    const float* __restrict__ x, __hip_bfloat16* __restrict__ xbf)
{
    int i = blockIdx.x * 256 + threadIdx.x;
    const int stride = gridDim.x * 256;
    const int n8 = B_ROWS * DDIM / 8;
    for (; i < n8; i += stride) {
        const float4 f0 = *(const float4*)(x + (size_t)i * 8);
        const float4 f1 = *(const float4*)(x + (size_t)i * 8 + 4);
        union { bf16x8 v; unsigned short u[8]; } pk;
        pk.u[0] = f2bf(f0.x); pk.u[1] = f2bf(f0.y); pk.u[2] = f2bf(f0.z); pk.u[3] = f2bf(f0.w);
        pk.u[4] = f2bf(f1.x); pk.u[5] = f2bf(f1.y); pk.u[6] = f2bf(f1.z); pk.u[7] = f2bf(f1.w);
        *(bf16x8*)((__hip_bfloat16*)xbf + (size_t)i * 8) = pk.v;
    }
}

// ---------------------------------------------------------------------------
// Pre-pass B: W [e][k][n] f32 -> Wt [e][n][k] bf16 via 64x64 LDS tile.
// ---------------------------------------------------------------------------
__global__ __launch_bounds__(256) void wtrans_kernel(
    const float* __restrict__ W, __hip_bfloat16* __restrict__ Wt)
{
    const int e  = blockIdx.z;
    const int k0 = blockIdx.y * 64;
    const int n0 = blockIdx.x * 64;
    __shared__ float st[64][65];          // +1 pad

    const int t = threadIdx.x;
    {
        const int kk = t >> 4;
        const int nn = (t & 15) * 4;
#pragma unroll
        for (int p = 0; p < 4; ++p) {
            const int k = p * 16 + kk;
            const float4 v = *(const float4*)(W + (size_t)e * DDIM * DDIM
                                                + (size_t)(k0 + k) * DDIM + n0 + nn);
            st[k][nn + 0] = v.x; st[k][nn + 1] = v.y;
            st[k][nn + 2] = v.z; st[k][nn + 3] = v.w;
        }
    }
    __syncthreads();
    {
        const int wave = t >> 6, lane = t & 63;
        const int nr = lane >> 3, kc = lane & 7;
#pragma unroll
        for (int p = 0; p < 2; ++p) {
            const int n = p * 32 + wave * 8 + nr;
            union { bf16x8 v; unsigned short u[8]; } pk;
#pragma unroll
            for (int j = 0; j < 8; ++j) pk.u[j] = f2bf(st[kc * 8 + j][n]);
            *(bf16x8*)((__hip_bfloat16*)Wt + (size_t)e * DDIM * DDIM
                        + (size_t)(n0 + n) * DDIM + k0 + kc * 8) = pk.v;
        }
    }
}

// ---------------------------------------------------------------------------
// Pre-pass C: replicated gate-weight layout: wtr[K8][c][j] = col_c[K8*8+j].
// 16 c-lanes read one contiguous 512B segment per K8 -> coalesced.
// ---------------------------------------------------------------------------
__global__ __launch_bounds__(256) void wprep_kernel(
    const float* __restrict__ wg, const float* __restrict__ wn, float* __restrict__ wtr)
{
    const int idx = blockIdx.x * 256 + threadIdx.x;   // 0..16383
    if (idx < 16 * DDIM) {
        const int k8  = idx >> 7;
        const int rem = idx & 127;
        const int c   = rem >> 3;
        const int j   = rem & 7;
        const int k   = k8 * 8 + j;
        wtr[idx] = (c < 8) ? wg[k * NEXP + c] : wn[k * NEXP + (c - 8)];
    }
}

// ---------------------------------------------------------------------------
// Kernel 1: gating v8 — matvec IDENTICAL to v7; output path is now plain
// per-row stores (ch[row] = e0|(e1<<8), gg[row] = {g0,g1}) with ZERO global
// atomics. (v5/v6/v7 all floored at ~150us with VALUBusy 7%: the 16K
// dependent atomicAdds to one cacheline were the serializer, not the loads.)
// ---------------------------------------------------------------------------
__global__ __launch_bounds__(256) void gating_kernel(
    const float* __restrict__ x, const float* __restrict__ noise,
    const float* __restrict__ wtr,
    int* __restrict__ ch, float2* __restrict__ gg)
{
    const int t = threadIdx.x;
    const int wave = t >> 6, lane = t & 63;
    const int ks = lane >> 5;          // bit 5
    const int rs = (lane >> 4) & 1;    // bit 4
    const int c  = lane & 15;          // bits 0-3
    const int row = blockIdx.x * 8 + wave * 2 + rs;

    const float* xr = x   + (size_t)row * DDIM + ks * 512;
    const float* wr = wtr + (size_t)ks * 8192 + c * 8;   // + k8*128 per octet

    double a0 = 0, a1 = 0, a2 = 0, a3 = 0, a4 = 0, a5 = 0, a6 = 0, a7 = 0;
    for (int ko = 0; ko < 16; ++ko) {            // 4 K8-octets per outer iter
        float4 xb[8], wb[8];
#pragma unroll
        for (int i = 0; i < 4; ++i) {
            const int k8 = ko * 4 + i;
            xb[2 * i]     = *(const float4*)(xr + k8 * 8);
            xb[2 * i + 1] = *(const float4*)(xr + k8 * 8 + 4);
            wb[2 * i]     = *(const float4*)(wr + k8 * 128);
            wb[2 * i + 1] = *(const float4*)(wr + k8 * 128 + 4);
        }
#pragma unroll
        for (int i = 0; i < 4; ++i) {
            a0 += (double)(xb[2 * i].x     * wb[2 * i].x);
            a1 += (double)(xb[2 * i].y     * wb[2 * i].y);
            a2 += (double)(xb[2 * i].z     * wb[2 * i].z);
            a3 += (double)(xb[2 * i].w     * wb[2 * i].w);
            a4 += (double)(xb[2 * i + 1].x * wb[2 * i + 1].x);
            a5 += (double)(xb[2 * i + 1].y * wb[2 * i + 1].y);
            a6 += (double)(xb[2 * i + 1].z * wb[2 * i + 1].z);
            a7 += (double)(xb[2 * i + 1].w * wb[2 * i + 1].w);
        }
    }
    double acc = ((a0 + a1) + (a2 + a3)) + ((a4 + a5) + (a6 + a7));

    // combine the two ks K-slices (bit 5; same rs,c)
    acc += __shfl_xor(acc, 32);

    const double vnoise = __shfl_xor(acc, 8);     // partner column c^8

    double lgv = -1.0e300;
    if (c < 8) {
        const double z  = vnoise;
        const double sp = (z > 30.0) ? z : log1p(exp(z));
        lgv = acc + (double)noise[(size_t)row * NEXP + c] * (sp + 0.01);
    }

    // top-1 butterfly over the 8 logit lanes (offsets 1,2,4; closed per rs,ks)
    double bv = lgv; int bi = c;
#pragma unroll
    for (int off = 1; off <= 4; off <<= 1) {
        const double ov = __shfl_xor(bv, off);
        const int    oi = __shfl_xor(bi, off);
        if (ov > bv || (ov == bv && oi < bi)) { bv = ov; bi = oi; }
    }
    // top-2: mask winner, reduce again
    double b2v = (c == bi) ? -1.0e300 : lgv; int b2i = c;
#pragma unroll
    for (int off = 1; off <= 4; off <<= 1) {
        const double ov = __shfl_xor(b2v, off);
        const int    oi = __shfl_xor(b2i, off);
        if (ov > b2v || (ov == b2v && oi < b2i)) { b2v = ov; b2i = oi; }
    }

    if ((lane & 47) == 0) {   // c==0 && ks==0 -> lanes 0 (rs0) and 16 (rs1)
        const double g0 = 1.0 / (1.0 + exp(b2v - bv));
        ch[row] = bi | (b2i << 8);
        gg[row] = make_float2((float)g0, (float)(1.0 - g0));
    }
}

// ---------------------------------------------------------------------------
// Kernel 1b: bin — deterministic stream compaction, zero atomics.
// One block, 8 waves; wave e owns expert e. 128 chunks of 64 rows: ballot
// over (e0==e) and (e1==e), prefix via popcount of lower-lane mask, scatter
// rowlist/gatelist, accumulate base. Lane 0 writes counts[e] at the end.
// rowlist entry = row | (rank<<31).
// ---------------------------------------------------------------------------
__global__ __launch_bounds__(512) void bin_kernel(
    const int* __restrict__ ch, const float2* __restrict__ gg,
    int* __restrict__ counts, int* __restrict__ rowlist, float* __restrict__ gatelist)
{
    const int e    = threadIdx.x >> 6;
    const int lane = threadIdx.x & 63;
    const unsigned long long ltmask = (1ull << lane) - 1ull;

    int base = 0;
    for (int chunk = 0; chunk < B_ROWS / 64; ++chunk) {
        const int row = chunk * 64 + lane;
        const int cv  = ch[row];
        const int e0  = cv & 255;
        const int e1  = (cv >> 8) & 255;
        const bool h0 = (e0 == e);
        const bool h1 = (e1 == e);
        const unsigned long long m0 = __ballot(h0);
        const unsigned long long m1 = __ballot(h1);
        const int n0 = __popcll(m0);
        if (h0) {
            const int pos = base + __popcll(m0 & ltmask);
            rowlist [e * B_ROWS + pos] = row;
            gatelist[e * B_ROWS + pos] = gg[row].x;
        }
        if (h1) {
            const int pos = base + n0 + __popcll(m1 & ltmask);
            rowlist [e * B_ROWS + pos] = (int)((unsigned)row | 0x80000000u);
            gatelist[e * B_ROWS + pos] = gg[row].y;
        }
        base += n0 + __popcll(m1);
    }
    if (lane == 0) counts[e] = base;
}

// ---------------------------------------------------------------------------
// Kernel 2: grouped expert GEMM, 128x128 tile, BK=64, single-buffer m97
// structure. Grid = (nt, e, mt) so the resident id-window is fully active.
// Epilogue: rank0 rows -> out, rank1 rows -> out2 (atomic-free).
// ---------------------------------------------------------------------------
__global__ __launch_bounds__(256) void moe_gemm_kernel(
    const __hip_bfloat16* __restrict__ xbf, const __hip_bfloat16* __restrict__ Wt,
    const float* __restrict__ bias,
    const int* __restrict__ counts, const int* __restrict__ rowlist,
    const float* __restrict__ gatelist, float* __restrict__ out, float* __restrict__ out2)
{
    const int nt = blockIdx.x;
    const int e  = blockIdx.y;
    const int mt = blockIdx.z;
    const int cnt  = counts[e];
    const int row0 = mt * 128;
    if (row0 >= cnt) return;

    __shared__ int   srow[128];
    __shared__ unsigned char srank[128];
    __shared__ float sgate[128];
    __shared__ __align__(16) unsigned char Alds[128 * 128];  // [row][64 bf16]
    __shared__ __align__(16) unsigned char Blds[128 * 128];  // [n][64 bf16]

    const int t = threadIdx.x;
    if (t < 128) {
        const int r = row0 + t;
        const unsigned er = (r < cnt) ? (unsigned)rowlist[e * B_ROWS + r] : 0u;
        srow[t]  = (int)(er & 0x7fffffffu);
        srank[t] = (unsigned char)(er >> 31);
        sgate[t] = (r < cnt) ? gatelist[e * B_ROWS + r] : 0.0f;
    }
    __syncthreads();

    const int wave = t >> 6, lane = t & 63;
    const int wr = wave >> 1, wc = wave & 1;
    const int l4 = lane >> 4, l16 = lane & 15;
    const int lrow  = lane >> 3;            // 0..7: row within 8-row stripe
    const int lchunk = (lane & 7) ^ lrow;   // inverse swizzle: slot s holds chunk s^row

    // per-lane byte source bases (constant over kt)
    const char* asrc[4]; const char* bsrc[4];
#pragma unroll
    for (int i = 0; i < 4; ++i) {
        const int r  = wave * 32 + i * 8 + lrow;
        asrc[i] = (const char*)xbf + 2 * ((size_t)srow[r] * DDIM + lchunk * 8);
        const int gn = nt * 128 + wave * 32 + i * 8 + lrow;
        bsrc[i] = (const char*)Wt  + 2 * ((size_t)e * DDIM * DDIM + (size_t)gn * DDIM + lchunk * 8);
    }

    f32x4 acc[4][4];
#pragma unroll
    for (int m = 0; m < 4; ++m)
#pragma unroll
        for (int n = 0; n < 4; ++n) acc[m][n] = (f32x4){0.f, 0.f, 0.f, 0.f};

    for (int kt = 0; kt < DDIM / 64; ++kt) {
        const int koff = kt * 128;  // bytes
#pragma unroll
        for (int i = 0; i < 4; ++i) {
            GLOAD_LDS16(asrc[i] + koff, Alds + (wave * 32 + i * 8) * 128);
            GLOAD_LDS16(bsrc[i] + koff, Blds + (wave * 32 + i * 8) * 128);
        }
        asm volatile("s_waitcnt vmcnt(0)" ::: "memory");
        __syncthreads();

#pragma unroll
        for (int ks = 0; ks < 2; ++ks) {
            bf16x8 af[4], bfr[4];
#pragma unroll
            for (int m = 0; m < 4; ++m) {
                const int row = wr * 64 + m * 16 + l16;
                af[m] = *(const bf16x8*)(Alds + row * 128 + ((ks * 64 + l4 * 16) ^ ((row & 7) << 4)));
            }
#pragma unroll
            for (int n = 0; n < 4; ++n) {
                const int rn = wc * 64 + n * 16 + l16;
                bfr[n] = *(const bf16x8*)(Blds + rn * 128 + ((ks * 64 + l4 * 16) ^ ((rn & 7) << 4)));
            }
#pragma unroll
            for (int m = 0; m < 4; ++m)
#pragma unroll
                for (int n = 0; n < 4; ++n)
                    acc[m][n] = __builtin_amdgcn_mfma_f32_16x16x32_bf16(af[m], bfr[n], acc[m][n], 0, 0, 0);
        }
        __syncthreads();
    }

    // ---- epilogue: dst[b,h] = g * exp(acc + bias), dst = rank ? out2 : out ----
#pragma unroll
    for (int m = 0; m < 4; ++m) {
#pragma unroll
        for (int n = 0; n < 4; ++n) {
#pragma unroll
            for (int j = 0; j < 4; ++j) {
                const int R = wr * 64 + m * 16 + l4 * 4 + j;   // C/D: row=(l>>4)*4+j, col=l&15
                if (row0 + R < cnt) {
                    const int   brow = srow[R];
                    const float g    = sgate[R];
                    const int   h    = nt * 128 + wc * 64 + n * 16 + l16;
                    const float v    = g * __expf(acc[m][n][j] + bias[e * DDIM + h]);
                    float* dst = srank[R] ? out2 : out;
                    dst[(size_t)brow * DDIM + h] = v;
                }
            }
        }
    }
}

// ---------------------------------------------------------------------------
// Kernel 3: out = log(out + out2), 0 -> EPS
// ---------------------------------------------------------------------------
__global__ __launch_bounds__(256) void logeps_kernel(
    float* __restrict__ o, const float* __restrict__ o2, int n4)
{
    const float EPSF = 2.220446049250313e-16f;  // np.finfo(float64).eps
    int i = blockIdx.x * blockDim.x + threadIdx.x;
    const int stride = gridDim.x * blockDim.x;
    float4* p = (float4*)o;
    const float4* q = (const float4*)o2;
    for (; i < n4; i += stride) {
        float4 a = p[i];
        const float4 b = q[i];
        a.x += b.x; a.y += b.y; a.z += b.z; a.w += b.w;
        a.x = __logf(a.x == 0.0f ? EPSF : a.x);
        a.y = __logf(a.y == 0.0f ? EPSF : a.y);
        a.z = __logf(a.z == 0.0f ? EPSF : a.z);
        a.w = __logf(a.w == 0.0f ? EPSF : a.w);
        p[i] = a;
    }
}

// ---------------------------------------------------------------------------
extern "C" void kernel_launch(void* const* d_in, const int* in_sizes, int n_in,
                              void* d_out, int out_size, void* d_ws, size_t ws_size,
                              hipStream_t stream)
{
    const float* x       = (const float*)d_in[0];
    const float* noise   = (const float*)d_in[1];
    const float* w_gate  = (const float*)d_in[2];
    const float* w_noise = (const float*)d_in[3];
    const float* W       = (const float*)d_in[4];
    const float* bias    = (const float*)d_in[5];
    float* out = (float*)d_out;

    char* ws = (char*)d_ws;
    int*    counts   = (int*)ws;                                   // 64 B
    float*  wtr      = (float*)(ws + 256);                         // 64 KB
    int*    rowlist  = (int*)(ws + 65792);                         // 256 KB
    float*  gatelist = (float*)(ws + 327936);                      // 256 KB
    int*    ch       = (int*)(ws + 590080);                        // 32 KB
    float2* gg       = (float2*)(ws + 622848);                     // 64 KB
    __hip_bfloat16* xbf = (__hip_bfloat16*)(ws + (1u << 20));                  // 16 MB
    __hip_bfloat16* Wt  = (__hip_bfloat16*)(ws + (1u << 20) + (16u << 20));    // 16 MB
    float* out2 = (float*)(ws + (1u << 20) + (32u << 20));                     // 32 MB

    wprep_kernel<<<64, 256, 0, stream>>>(w_gate, w_noise, wtr);
    gating_kernel<<<B_ROWS / 8, 256, 0, stream>>>(x, noise, wtr, ch, gg);
    xconv_kernel<<<1024, 256, 0, stream>>>(x, xbf);
    wtrans_kernel<<<dim3(16, 16, NEXP), 256, 0, stream>>>(W, Wt);
    bin_kernel<<<1, 512, 0, stream>>>(ch, gg, counts, rowlist, gatelist);

    dim3 grid(NEXP /*nt*/, NEXP /*e*/, B_ROWS / 128 /*mt*/);
    moe_gemm_kernel<<<grid, 256, 0, stream>>>(xbf, Wt, bias, counts, rowlist, gatelist,
                                              out, out2);

    logeps_kernel<<<2048, 256, 0, stream>>>(out, out2, out_size / 4);
}